// Round 8
// baseline (741.536 us; speedup 1.0000x reference)
//
#include <hip/hip_runtime.h>
#include <hip/hip_fp16.h>

#define DI __device__ __forceinline__

typedef _Float16 f16x8 __attribute__((ext_vector_type(8)));
typedef float f32x4 __attribute__((ext_vector_type(4)));

struct alignas(8) h4 { __half x, y, z, w; };

DI float waveReduceSum(float v) {
#pragma unroll
  for (int i = 1; i < 64; i <<= 1) v += __shfl_xor(v, i);
  return v;
}
DI float waveReduceMax(float v) {
#pragma unroll
  for (int i = 1; i < 64; i <<= 1) v = fmaxf(v, __shfl_xor(v, i));
  return v;
}

DI float gelu_exact(float x) { return 0.5f * x * (1.f + erff(x * 0.70710678118654752f)); }

#define MFMA16(b_, a_, c_) __builtin_amdgcn_mfma_f32_16x16x32_f16((b_), (a_), (c_), 0, 0, 0)

// ---------------------------------------------------------------------------
// gemm_nt8 — R5 structure (716 TF best measured on qk; R7 measured 124us on
// identical source = co-compilation variance, rule #19 — stop tuning this).
// 256x256 tile, BK=64, 512 thr, reg-staged LDS dbuf, 1 barrier/K-tile.
// + bijective XCD swizzle (gridDim.x % 8 == 0 for all launches).
// ---------------------------------------------------------------------------
template <typename CT, bool BIAS, bool BROW>
__global__ __launch_bounds__(512, 2) void gemm_nt8(
    const __half* __restrict__ A, int lda, long long sA,
    const __half* __restrict__ Bt, int ldb, long long sB,
    const float* __restrict__ bias, long long sBias,
    CT* __restrict__ C, int ldc, long long sC,
    int nT, int K) {
  __shared__ __align__(16) __half As[2][16384];  // 2 slots x 256x64
  __shared__ __align__(16) __half Bs[2][16384];

  const int tid = threadIdx.x;
  const int wave = tid >> 6, lane = tid & 63;

  // bijective XCD swizzle: blocks resident on one XCD get contiguous tile ids
  const int cpx = gridDim.x >> 3;
  const int bid = (blockIdx.x & 7) * cpx + (blockIdx.x >> 3);

  // GROUP_M=4 swizzled block decode (all mT here divisible by 4)
  const int gsz = 4 * nT;
  const int g = bid / gsz, r = bid % gsz;
  const int m0 = (g * 4 + (r & 3)) * 256;
  const int n0 = (r >> 2) * 256;

  A += (long long)blockIdx.z * sA;
  Bt += (long long)blockIdx.z * sB;
  C += (long long)blockIdx.z * sC;
  if constexpr (BIAS || BROW) bias += (long long)blockIdx.z * sBias;

  const int wm = wave >> 2, wn = wave & 3;

  f32x4 acc[8][4];
#pragma unroll
  for (int i = 0; i < 8; ++i)
#pragma unroll
    for (int j = 0; j < 4; ++j) acc[i][j] = (f32x4){0.f, 0.f, 0.f, 0.f};

  // staging: load-chunk j of thread t maps to rows j*64 + (t>>3); slot col
  // (t&7) holds global chunk (t&7)^((t>>3)&7). 512 thr x 16B = 64 rows/chunk.
  const int srow = tid >> 3;
  const int gc = (tid & 7) ^ (srow & 7);
  const __half* Ag = A + (size_t)(m0 + srow) * lda + gc * 8;
  const __half* Bg = Bt + (size_t)(n0 + srow) * ldb + gc * 8;
  const size_t a64 = (size_t)64 * lda, b64 = (size_t)64 * ldb;
  char* AsWr = (char*)As + tid * 16;  // linear layout
  char* BsWr = (char*)Bs + tid * 16;

  f16x8 sra[4], srb[4];  // in-flight staging registers (one K-tile)

#define LDG(t)                                                        \
  {                                                                   \
    const __half* sa_ = Ag + (t) * 64;                                \
    const __half* sb_ = Bg + (t) * 64;                                \
    sra[0] = *(const f16x8*)(sa_);                                    \
    sra[1] = *(const f16x8*)(sa_ + a64);                              \
    sra[2] = *(const f16x8*)(sa_ + 2 * a64);                          \
    sra[3] = *(const f16x8*)(sa_ + 3 * a64);                          \
    srb[0] = *(const f16x8*)(sb_);                                    \
    srb[1] = *(const f16x8*)(sb_ + b64);                              \
    srb[2] = *(const f16x8*)(sb_ + 2 * b64);                          \
    srb[3] = *(const f16x8*)(sb_ + 3 * b64);                          \
  }
#define DSW(t)                                                        \
  {                                                                   \
    char* da_ = AsWr + (((t) & 1) ? 32768 : 0);                       \
    char* db_ = BsWr + (((t) & 1) ? 32768 : 0);                       \
    *(f16x8*)(da_) = sra[0];                                          \
    *(f16x8*)(da_ + 8192) = sra[1];                                   \
    *(f16x8*)(da_ + 16384) = sra[2];                                  \
    *(f16x8*)(da_ + 24576) = sra[3];                                  \
    *(f16x8*)(db_) = srb[0];                                          \
    *(f16x8*)(db_ + 8192) = srb[1];                                   \
    *(f16x8*)(db_ + 16384) = srb[2];                                  \
    *(f16x8*)(db_ + 24576) = srb[3];                                  \
  }

  // frag read bases: A row = wm*128 + mi*16 + ml; B row = wn*64 + nj*16 + ml.
  const int ml = lane & 15, q = lane >> 4, lx = lane & 7;
  const int co0 = (q ^ lx) * 16, co1 = co0 ^ 64;
  const char* Ar = (const char*)As + wm * 16384 + ml * 128;
  const char* Br = (const char*)Bs + (wn >> 1) * 16384 + (wn & 1) * 8192 + ml * 128;

  const int nt = K >> 6;
  LDG(0);
  DSW(0);
  if (nt > 1) LDG(1);
  asm volatile("s_waitcnt lgkmcnt(0)" ::: "memory");
  __builtin_amdgcn_s_barrier();
  __builtin_amdgcn_sched_barrier(0);

  for (int t = 0; t < nt; ++t) {
    if (t + 1 < nt) {
      DSW(t + 1);
      if (t + 2 < nt) LDG(t + 2);
    }
    const int pb = (t & 1) ? 32768 : 0;
    const char* Ap = Ar + pb;
    const char* Bp = Br + pb;
    f16x8 af[8], bf[4];
#pragma unroll
    for (int ks = 0; ks < 2; ++ks) {
      const int co = ks ? co1 : co0;
#pragma unroll
      for (int i = 0; i < 8; ++i) af[i] = *(const f16x8*)(Ap + i * 2048 + co);
#pragma unroll
      for (int j = 0; j < 4; ++j) bf[j] = *(const f16x8*)(Bp + j * 2048 + co);
#pragma unroll
      for (int i = 0; i < 8; ++i)
#pragma unroll
        for (int j = 0; j < 4; ++j)
          acc[i][j] = MFMA16(bf[j], af[i], acc[i][j]);
    }
    asm volatile("s_waitcnt lgkmcnt(0)" ::: "memory");
    __builtin_amdgcn_s_barrier();
    __builtin_amdgcn_sched_barrier(0);
  }
#undef LDG
#undef DSW

  // epilogue (swapped layout): frag (i,j) holds C[m0+wm*128+i*16+ml]
  // [n0+wn*64+j*16+q*4 + rr] -> packed 8B/16B stores.
#pragma unroll
  for (int j = 0; j < 4; ++j) {
    const int col0 = n0 + wn * 64 + j * 16 + q * 4;
    float4 bc = {0.f, 0.f, 0.f, 0.f};
    if constexpr (BIAS) bc = *(const float4*)(bias + col0);
#pragma unroll
    for (int i = 0; i < 8; ++i) {
      const int row = m0 + wm * 128 + i * 16 + ml;
      const float br = BROW ? bias[row] : 0.f;
      const float v0 = acc[i][j][0] + bc.x + br;
      const float v1 = acc[i][j][1] + bc.y + br;
      const float v2 = acc[i][j][2] + bc.z + br;
      const float v3 = acc[i][j][3] + bc.w + br;
      if constexpr (sizeof(CT) == 4) {
        *(float4*)(C + (size_t)row * ldc + col0) = make_float4(v0, v1, v2, v3);
      } else {
        h4 o{__float2half(v0), __float2half(v1), __float2half(v2), __float2half(v3)};
        *(h4*)((__half*)C + (size_t)row * ldc + col0) = o;
      }
    }
  }
}

// ---------------------------------------------------------------------------
// gemm_nt — 128x128. R8: single 32KB LDS buffer + __launch_bounds__(256,3)
// -> 3 blocks/CU (12 waves) so OTHER blocks' MFMAs cover each block's
// stage->read turnaround (m97/m114 TLP mechanism). Keeps reg-staging: LDG of
// tile t+1 issued under tile t's MFMAs; 2 lgkm-fenced barriers per K-tile:
//   DSW(t) -> lgkm0 -> bar -> LDG(t+1) -> MFMA(t) -> lgkm0 -> bar
// R7 (dbuf, 2 blk/CU) spent LDS on ILP that R2-R6 proved doesn't pay, at the
// cost of the TLP that does. + bijective XCD swizzle.
// ---------------------------------------------------------------------------
template <typename CT, bool BIAS, bool BROW>
__global__ __launch_bounds__(256, 3) void gemm_nt(
    const __half* __restrict__ A, int lda, long long sA,
    const __half* __restrict__ Bt, int ldb, long long sB,
    const float* __restrict__ bias, long long sBias,
    CT* __restrict__ C, int ldc, long long sC,
    int nT, int K) {
  __shared__ __align__(16) __half As[8192];  // 16KB
  __shared__ __align__(16) __half Bs[8192];  // 16KB

  const int tid = threadIdx.x;
  const int wave = tid >> 6, lane = tid & 63;

  // bijective XCD swizzle (all launch grids % 8 == 0)
  const int cpx = gridDim.x >> 3;
  const int bid = (blockIdx.x & 7) * cpx + (blockIdx.x >> 3);

  const int gsz = 8 * nT;
  const int g = bid / gsz, r = bid % gsz;
  const int m0 = (g * 8 + (r & 7)) * 128;
  const int n0 = (r >> 3) * 128;

  A += (long long)blockIdx.z * sA;
  Bt += (long long)blockIdx.z * sB;
  C += (long long)blockIdx.z * sC;
  if constexpr (BIAS || BROW) bias += (long long)blockIdx.z * sBias;
  const int wm = wave & 1, wn = wave >> 1;

  f32x4 acc[4][4];
#pragma unroll
  for (int i = 0; i < 4; ++i)
#pragma unroll
    for (int jj = 0; jj < 4; ++jj) acc[i][jj] = (f32x4){0.f, 0.f, 0.f, 0.f};

  // staging: chunk i of thread t covers rows i*32 + (t>>3); slot col (t&7)
  // holds global chunk (t&7)^(row&7). 256 thr x 16B = 32 rows / chunk.
  const int srow = tid >> 3;
  const int gc = (tid & 7) ^ (srow & 7);
  const __half* Ag = A + (size_t)(m0 + srow) * lda + gc * 8;
  const __half* Bg = Bt + (size_t)(n0 + srow) * ldb + gc * 8;
  const size_t a32 = (size_t)32 * lda, b32 = (size_t)32 * ldb;
  char* AsWr = (char*)As + tid * 16;
  char* BsWr = (char*)Bs + tid * 16;

  f16x8 sra[4], srb[4];

#define LDG(t)                                                        \
  {                                                                   \
    const __half* sa_ = Ag + (t) * 64;                                \
    const __half* sb_ = Bg + (t) * 64;                                \
    sra[0] = *(const f16x8*)(sa_);                                    \
    sra[1] = *(const f16x8*)(sa_ + a32);                              \
    sra[2] = *(const f16x8*)(sa_ + 2 * a32);                          \
    sra[3] = *(const f16x8*)(sa_ + 3 * a32);                          \
    srb[0] = *(const f16x8*)(sb_);                                    \
    srb[1] = *(const f16x8*)(sb_ + b32);                              \
    srb[2] = *(const f16x8*)(sb_ + 2 * b32);                          \
    srb[3] = *(const f16x8*)(sb_ + 3 * b32);                          \
  }
#define DSW()                                                         \
  {                                                                   \
    *(f16x8*)(AsWr) = sra[0];                                         \
    *(f16x8*)(AsWr + 4096) = sra[1];                                  \
    *(f16x8*)(AsWr + 8192) = sra[2];                                  \
    *(f16x8*)(AsWr + 12288) = sra[3];                                 \
    *(f16x8*)(BsWr) = srb[0];                                         \
    *(f16x8*)(BsWr + 4096) = srb[1];                                  \
    *(f16x8*)(BsWr + 8192) = srb[2];                                  \
    *(f16x8*)(BsWr + 12288) = srb[3];                                 \
  }

  const int ml = lane & 15, q = lane >> 4, lx = lane & 7;
  const int aoff = ((wm * 64 + ml) * 8 + (q ^ lx)) * 16;
  const int boff = ((wn * 64 + ml) * 8 + (q ^ lx)) * 16;

  const int nt = K >> 6;
  LDG(0);
  for (int t = 0; t < nt; ++t) {
    // write tile t (prev iter's closing barrier guarantees all reads done;
    // compiler inserts the vmcnt wait for sra/srb)
    DSW();
    asm volatile("s_waitcnt lgkmcnt(0)" ::: "memory");
    __builtin_amdgcn_s_barrier();
    __builtin_amdgcn_sched_barrier(0);
    // issue next tile's loads; they fly under this tile's MFMAs
    if (t + 1 < nt) LDG(t + 1);
#pragma unroll
    for (int jj = 0; jj < 2; ++jj) {
      const char* Ab = (const char*)As + (jj ? (aoff ^ 64) : aoff);
      const char* Bb = (const char*)Bs + (jj ? (boff ^ 64) : boff);
      f16x8 af[4], bf[4];
#pragma unroll
      for (int i = 0; i < 4; ++i) {
        af[i] = *(const f16x8*)(Ab + i * 2048);
        bf[i] = *(const f16x8*)(Bb + i * 2048);
      }
#pragma unroll
      for (int i = 0; i < 4; ++i)
#pragma unroll
        for (int jn = 0; jn < 4; ++jn)
          acc[i][jn] = MFMA16(bf[jn], af[i], acc[i][jn]);
    }
    asm volatile("s_waitcnt lgkmcnt(0)" ::: "memory");
    __builtin_amdgcn_s_barrier();
    __builtin_amdgcn_sched_barrier(0);
  }
#undef LDG
#undef DSW

  // swapped-layout packed epilogue
#pragma unroll
  for (int jn = 0; jn < 4; ++jn) {
    const int col0 = n0 + wn * 64 + jn * 16 + q * 4;
    float4 bc = {0.f, 0.f, 0.f, 0.f};
    if constexpr (BIAS) bc = *(const float4*)(bias + col0);
#pragma unroll
    for (int i = 0; i < 4; ++i) {
      const int row = m0 + wm * 64 + i * 16 + ml;
      const float br = BROW ? bias[row] : 0.f;
      const float v0 = acc[i][jn][0] + bc.x + br;
      const float v1 = acc[i][jn][1] + bc.y + br;
      const float v2 = acc[i][jn][2] + bc.z + br;
      const float v3 = acc[i][jn][3] + bc.w + br;
      if constexpr (sizeof(CT) == 4) {
        *(float4*)(C + (size_t)row * ldc + col0) = make_float4(v0, v1, v2, v3);
      } else {
        h4 o{__float2half(v0), __float2half(v1), __float2half(v2), __float2half(v3)};
        *(h4*)((__half*)C + (size_t)row * ldc + col0) = o;
      }
    }
  }
}

// ---------------------------------------------------------------------------
// prep: all 6 weight transposes (fp32 -> fp16) + bias concat. grid (2305, 6).
// ---------------------------------------------------------------------------
__global__ __launch_bounds__(256) void prep(
    const float* __restrict__ Wq, const float* __restrict__ Wk,
    const float* __restrict__ Wv, const float* __restrict__ W1,
    const float* __restrict__ Wo, const float* __restrict__ W2,
    const float* __restrict__ bq, const float* __restrict__ bk,
    __half* __restrict__ wD, __half* __restrict__ wB, __half* __restrict__ wC,
    __half* __restrict__ wA, float* __restrict__ bqk) {
  if (blockIdx.x == 2304) {
    if (blockIdx.y == 0)
      for (int i = threadIdx.x; i < 3072; i += 256) {
        bqk[i] = bq[i];
        bqk[3072 + i] = bk[i];
      }
    return;
  }
  __shared__ float t[32][33];
  const int tx = threadIdx.x & 31, ty = threadIdx.x >> 5;
  if (blockIdx.y < 4) {
    const float* in;
    __half* out;
    switch (blockIdx.y) {
      case 0: in = Wq; out = wD; break;
      case 1: in = Wk; out = wD + 3072 * 768; break;
      case 2: in = Wv; out = wB; break;
      default: in = W1; out = wC; break;
    }
    const int cb = blockIdx.x % 96, rb = blockIdx.x / 96;
    const int c = cb * 32 + tx, r0 = rb * 32;
#pragma unroll
    for (int i = 0; i < 32; i += 8) t[ty + i][tx] = in[(size_t)(r0 + ty + i) * 3072 + c];
    __syncthreads();
    const int oc = r0 + tx, o0 = cb * 32;
#pragma unroll
    for (int i = 0; i < 32; i += 8)
      out[(size_t)(o0 + ty + i) * 768 + oc] = __float2half(t[tx][ty + i]);
  } else {
    const float* in = (blockIdx.y == 5) ? W2 : Wo;
    __half* out = wA + ((blockIdx.y == 5) ? 3072 * 768 : 0);
    const int cb = blockIdx.x % 24, rb = blockIdx.x / 24;
    const int c = cb * 32 + tx, r0 = rb * 32;
#pragma unroll
    for (int i = 0; i < 32; i += 8) t[ty + i][tx] = in[(size_t)(r0 + ty + i) * 768 + c];
    __syncthreads();
    const int oc = r0 + tx, o0 = cb * 32;
#pragma unroll
    for (int i = 0; i < 32; i += 8)
      out[(size_t)(o0 + ty + i) * 3072 + oc] = __float2half(t[tx][ty + i]);
  }
}

// ---------------------------------------------------------------------------
__global__ __launch_bounds__(256) void embed_pos_kernel(
    const int* __restrict__ x, const float* __restrict__ emb,
    float* __restrict__ y, __half* __restrict__ yh) {
  const int row = blockIdx.x;  // b*1024 + s
  const int s = row & 1023;
  const int tok = x[row];
  const float* ep = emb + (size_t)tok * 768;
  float* yp = y + (size_t)row * 768;
  __half* hp = yh + (size_t)row * 768;
  const float c = -13.287712379549449f / 768.f;  // -log2(10000)/768
  for (int d = threadIdx.x; d < 768; d += 256) {
    float ang = (float)s * exp2f((float)d * c);
    float pe = (d & 1) ? cosf(ang) : sinf(ang);
    float v = ep[d] + pe;
    yp[d] = v;
    hp[d] = __float2half(v);
  }
}

// Row softmax over 1024 fp32 logits -> fp16 probs. One block per row.
__global__ __launch_bounds__(256) void softmax_rows(
    const float* __restrict__ L, __half* __restrict__ P) {
  const size_t row = blockIdx.x;
  const float4 x = ((const float4*)(L + row * 1024))[threadIdx.x];
  const int wave = threadIdx.x >> 6, lane = threadIdx.x & 63;
  float m = fmaxf(fmaxf(x.x, x.y), fmaxf(x.z, x.w));
  m = waveReduceMax(m);
  __shared__ float sm[4];
  __shared__ float ssum[4];
  if (lane == 0) sm[wave] = m;
  __syncthreads();
  m = fmaxf(fmaxf(sm[0], sm[1]), fmaxf(sm[2], sm[3]));
  float e0 = expf(x.x - m), e1 = expf(x.y - m), e2 = expf(x.z - m), e3 = expf(x.w - m);
  float s = e0 + e1 + e2 + e3;
  s = waveReduceSum(s);
  if (lane == 0) ssum[wave] = s;
  __syncthreads();
  s = ssum[0] + ssum[1] + ssum[2] + ssum[3];
  const float inv = 1.f / s;
  h4 o{__float2half(e0 * inv), __float2half(e1 * inv), __float2half(e2 * inv),
       __float2half(e3 * inv)};
  ((h4*)(P + row * 1024))[threadIdx.x] = o;
}

// y += [gelu](p0 + p1 + bias[d]) in-place + layernorm2d partial sums.
template <bool GELU>
__global__ __launch_bounds__(256) void residual_stats(
    float* __restrict__ y, const float* __restrict__ p0, const float* __restrict__ p1,
    const float* __restrict__ bias, float2* __restrict__ partials) {
  const int b = blockIdx.y, chunk = blockIdx.x;
  const size_t base = (size_t)b * 786432 + (size_t)chunk * 8192;
  float4* yp = (float4*)(y + base);
  const float4* a0 = (const float4*)(p0 + base);
  const float4* a1 = (const float4*)(p1 + base);
  float s = 0.f, ss = 0.f;
#pragma unroll
  for (int it = 0; it < 8; ++it) {
    const int idx = it * 256 + threadIdx.x;
    const int d = (chunk * 8192 + it * 1024 + threadIdx.x * 4) % 768;
    float4 yv = yp[idx];
    float4 v0 = a0[idx];
    float4 v1 = a1[idx];
    const float4 bv = *(const float4*)(bias + d);
    float ax = v0.x + v1.x + bv.x, ay = v0.y + v1.y + bv.y;
    float az = v0.z + v1.z + bv.z, aw = v0.w + v1.w + bv.w;
    if constexpr (GELU) {
      ax = gelu_exact(ax); ay = gelu_exact(ay);
      az = gelu_exact(az); aw = gelu_exact(aw);
    }
    float4 r{yv.x + ax, yv.y + ay, yv.z + az, yv.w + aw};
    yp[idx] = r;
    s += r.x + r.y + r.z + r.w;
    ss += r.x * r.x + r.y * r.y + r.z * r.z + r.w * r.w;
  }
  s = waveReduceSum(s);
  ss = waveReduceSum(ss);
  __shared__ float2 wr[4];
  const int wave = threadIdx.x >> 6, lane = threadIdx.x & 63;
  if (lane == 0) wr[wave] = make_float2(s, ss);
  __syncthreads();
  if (threadIdx.x == 0) {
    float S = wr[0].x + wr[1].x + wr[2].x + wr[3].x;
    float SS = wr[0].y + wr[1].y + wr[2].y + wr[3].y;
    partials[b * 96 + chunk] = make_float2(S, SS);
  }
}

// Finalize (reduce 96 partials in-block) + apply LN; grid 6144.
template <bool WB>
__global__ __launch_bounds__(256) void ln_apply(
    float* __restrict__ y, __half* __restrict__ yh, const float* __restrict__ w,
    const float* __restrict__ bb, const float2* __restrict__ partials) {
  const unsigned i4 = blockIdx.x * 256 + threadIdx.x;
  const unsigned i = i4 * 4;
  const unsigned b = i / 786432u;
  const int tid = threadIdx.x;
  float s = 0.f, ss = 0.f;
  if (tid < 96) {
    float2 p = partials[b * 96 + tid];
    s = p.x;
    ss = p.y;
  }
  s = waveReduceSum(s);
  ss = waveReduceSum(ss);
  __shared__ float2 wsum[4];
  if ((tid & 63) == 0) wsum[tid >> 6] = make_float2(s, ss);
  __syncthreads();
  const float S = wsum[0].x + wsum[1].x + wsum[2].x + wsum[3].x;
  const float SS = wsum[0].y + wsum[1].y + wsum[2].y + wsum[3].y;
  const float inv = 1.f / 786432.f;
  const float mean = S * inv;
  const float rstd = rsqrtf(SS * inv - mean * mean + 1e-5f);

  const unsigned e4 = (i - b * 786432u) >> 2;
  float4 yv = ((const float4*)y)[i4];
  const float4 wv = ((const float4*)w)[e4];
  const float4 bv = ((const float4*)bb)[e4];
  float4 r;
  r.x = (yv.x - mean) * rstd * wv.x + bv.x;
  r.y = (yv.y - mean) * rstd * wv.y + bv.y;
  r.z = (yv.z - mean) * rstd * wv.z + bv.z;
  r.w = (yv.w - mean) * rstd * wv.w + bv.w;
  ((float4*)y)[i4] = r;
  if constexpr (WB) {
    h4 o{__float2half(r.x), __float2half(r.y), __float2half(r.z), __float2half(r.w)};
    ((h4*)yh)[i4] = o;
  }
}

// ---------------------------------------------------------------------------
extern "C" void kernel_launch(void* const* d_in, const int* in_sizes, int n_in,
                              void* d_out, int out_size, void* d_ws, size_t ws_size,
                              hipStream_t stream) {
  const int* x = (const int*)d_in[0];
  const float* emb = (const float*)d_in[1];
  const float* Wq = (const float*)d_in[2];
  const float* bq = (const float*)d_in[3];
  const float* Wk = (const float*)d_in[4];
  const float* bk = (const float*)d_in[5];
  const float* Wv = (const float*)d_in[6];
  const float* bv = (const float*)d_in[7];
  const float* Wo = (const float*)d_in[8];
  const float* bo = (const float*)d_in[9];
  const float* W1 = (const float*)d_in[10];
  const float* b1 = (const float*)d_in[11];
  const float* W2 = (const float*)d_in[12];
  const float* b2 = (const float*)d_in[13];
  const float* ln1w = (const float*)d_in[14];
  const float* ln1b = (const float*)d_in[15];
  const float* ln2w = (const float*)d_in[16];
  const float* ln2b = (const float*)d_in[17];

  float* y = (float*)d_out;  // [8,1024,768] fp32 residual stream

  // ---- workspace map (liveness overlays), total 225.5 MB ----
  char* ws = (char*)d_ws;
  __half* yh = (__half*)(ws + 0);            // 12.58 MB fp16 residual stream
  __half* qb = (__half*)(ws + 12582912);     // 50.33 MB q -> av -> f1
  __half* kb = (__half*)(ws + 62914560);     // 50.33 MB k -> Ph
  __half* Ph = kb;
  __half* vT = (__half*)(ws + 113246208);    // 50.33 MB v^T -> abuf (2x25.17 split-K)
  float* abuf = (float*)vT;
  float* Lg = (float*)(ws + 163577856);      // 33.55 MB logits fp32
  __half* wA = (__half*)(ws + 197132288);    // 9.44 MB Wo^T|W2^T
  __half* wD = (__half*)(ws + 206569472);    // 9.44 MB Wq^T|Wk^T
  __half* wB = (__half*)(ws + 216006656);    // 4.72 MB Wv^T
  __half* wC = (__half*)(ws + 220725248);    // 4.72 MB W1^T
  float* bqk = (float*)(ws + 225443840);     // 24 KB bq|bk
  float2* part = (float2*)(ws + 225468416);  // 6 KB
  const size_t WS_NEEDED = 225474624;
  if (ws_size < WS_NEEDED) return;

  const dim3 blk(256), blk8(512);
  const long long SH = 1024LL * 3072, SS = 1024LL * 1024;
  const long long HALF = 25165824;  // q->k element stride (8192*3072)
  float* p1 = abuf + 6291456;       // second split-K partial

  prep<<<dim3(2305, 6), blk, 0, stream>>>(Wq, Wk, Wv, W1, Wo, W2, bq, bk, wD, wB, wC, wA, bqk);
  embed_pos_kernel<<<dim3(8192), blk, 0, stream>>>(x, emb, y, yh);

  // q,k = yh @ {Wq,Wk} + {bq,bk}: M=8192 N=3072 K=768 (768 blocks = 3 rounds)
  gemm_nt8<__half, true, false><<<dim3(384, 1, 2), blk8, 0, stream>>>(
      yh, 768, 0, wD, 768, 3072LL * 768, bqk, 3072, qb, 3072, HALF, 12, 768);

  // vT[b][n][s] = sum_k Wv[k][n]*y[b][s][k] + bv[n]  (128^2: 1536 blocks)
  gemm_nt<__half, false, true><<<dim3(192, 1, 8), blk, 0, stream>>>(
      wB, 768, 0, yh, 768, 1024LL * 768, bv, 0, vT, 1024, SH, 8, 768);

  // logits = q k^T (fp32), per batch (128^2: 512 blocks)
  gemm_nt<float, false, false><<<dim3(64, 1, 8), blk, 0, stream>>>(
      qb, 3072, SH, kb, 3072, SH, nullptr, 0, Lg, 1024, SS, 8, 3072);

  softmax_rows<<<dim3(8192), blk, 0, stream>>>(Lg, Ph);  // Ph overlays k (dead)

  // av = P @ V (Bt = v^T), per batch (128^2: 1536 blocks); av overlays q
  gemm_nt<__half, false, false><<<dim3(192, 1, 8), blk, 0, stream>>>(
      Ph, 1024, SS, vT, 1024, SH, nullptr, 0, (__half*)qb, 3072, SH, 24, 1024);

  // a = av @ Wo (split-K=2, 128^2: 768 blocks) -> abuf over vT
  gemm_nt<float, false, false><<<dim3(384, 1, 2), blk, 0, stream>>>(
      (__half*)qb, 3072, 1536, wA, 3072, 1536, nullptr, 0, abuf, 768, 6291456, 6, 1536);

  // y = ln1(y + a + bo)
  residual_stats<false><<<dim3(96, 8), blk, 0, stream>>>(y, abuf, p1, bo, part);
  ln_apply<true><<<dim3(6144), blk, 0, stream>>>(y, yh, ln1w, ln1b, part);

  // f1 = y@W1 + b1 (128^2: 1536 blocks)
  gemm_nt<__half, true, false><<<dim3(1536, 1, 1), blk, 0, stream>>>(
      yh, 768, 0, wC, 768, 0, b1, 0, (__half*)qb, 3072, 0, 24, 768);
  // f = f1@W2 (split-K=2, 128^2: 768 blocks; bias b2 + gelu in residual) -> abuf
  gemm_nt<float, false, false><<<dim3(384, 1, 2), blk, 0, stream>>>(
      (__half*)qb, 3072, 1536, wA + 3072 * 768, 3072, 1536, nullptr, 0, abuf, 768, 6291456, 6, 1536);

  // y = ln2(y + gelu(f + b2))
  residual_stats<true><<<dim3(96, 8), blk, 0, stream>>>(y, abuf, p1, b2, part);
  ln_apply<false><<<dim3(6144), blk, 0, stream>>>(y, nullptr, ln2w, ln2b, part);
}

// Round 9
// 705.973 us; speedup vs baseline: 1.0504x; 1.0504x over previous
//
#include <hip/hip_runtime.h>
#include <hip/hip_fp16.h>

#define DI __device__ __forceinline__

typedef _Float16 f16x8 __attribute__((ext_vector_type(8)));
typedef float f32x4 __attribute__((ext_vector_type(4)));

struct alignas(8) h4 { __half x, y, z, w; };

DI float waveReduceSum(float v) {
#pragma unroll
  for (int i = 1; i < 64; i <<= 1) v += __shfl_xor(v, i);
  return v;
}
DI float waveReduceMax(float v) {
#pragma unroll
  for (int i = 1; i < 64; i <<= 1) v = fmaxf(v, __shfl_xor(v, i));
  return v;
}

DI float gelu_exact(float x) { return 0.5f * x * (1.f + erff(x * 0.70710678118654752f)); }

#define MFMA16(b_, a_, c_) __builtin_amdgcn_mfma_f32_16x16x32_f16((b_), (a_), (c_), 0, 0, 0)

// ---------------------------------------------------------------------------
// gemm_nt8 — R5/R8 structure (716 TF best on qk; 108-124us band is
// co-compilation noise, rule #19). 256x256, BK=64, 512 thr, reg-staged dbuf,
// 1 barrier/K-tile, bijective XCD swizzle, packed swapped-operand epilogue.
// ---------------------------------------------------------------------------
template <typename CT, bool BIAS, bool BROW>
__global__ __launch_bounds__(512, 2) void gemm_nt8(
    const __half* __restrict__ A, int lda, long long sA,
    const __half* __restrict__ Bt, int ldb, long long sB,
    const float* __restrict__ bias, long long sBias,
    CT* __restrict__ C, int ldc, long long sC,
    int nT, int K) {
  __shared__ __align__(16) __half As[2][16384];
  __shared__ __align__(16) __half Bs[2][16384];

  const int tid = threadIdx.x;
  const int wave = tid >> 6, lane = tid & 63;

  const int cpx = gridDim.x >> 3;
  const int bid = (blockIdx.x & 7) * cpx + (blockIdx.x >> 3);

  const int gsz = 4 * nT;
  const int g = bid / gsz, r = bid % gsz;
  const int m0 = (g * 4 + (r & 3)) * 256;
  const int n0 = (r >> 2) * 256;

  A += (long long)blockIdx.z * sA;
  Bt += (long long)blockIdx.z * sB;
  C += (long long)blockIdx.z * sC;
  if constexpr (BIAS || BROW) bias += (long long)blockIdx.z * sBias;

  const int wm = wave >> 2, wn = wave & 3;

  f32x4 acc[8][4];
#pragma unroll
  for (int i = 0; i < 8; ++i)
#pragma unroll
    for (int j = 0; j < 4; ++j) acc[i][j] = (f32x4){0.f, 0.f, 0.f, 0.f};

  const int srow = tid >> 3;
  const int gc = (tid & 7) ^ (srow & 7);
  const __half* Ag = A + (size_t)(m0 + srow) * lda + gc * 8;
  const __half* Bg = Bt + (size_t)(n0 + srow) * ldb + gc * 8;
  const size_t a64 = (size_t)64 * lda, b64 = (size_t)64 * ldb;
  char* AsWr = (char*)As + tid * 16;
  char* BsWr = (char*)Bs + tid * 16;

  f16x8 sra[4], srb[4];

#define LDG(t)                                                        \
  {                                                                   \
    const __half* sa_ = Ag + (t) * 64;                                \
    const __half* sb_ = Bg + (t) * 64;                                \
    sra[0] = *(const f16x8*)(sa_);                                    \
    sra[1] = *(const f16x8*)(sa_ + a64);                              \
    sra[2] = *(const f16x8*)(sa_ + 2 * a64);                          \
    sra[3] = *(const f16x8*)(sa_ + 3 * a64);                          \
    srb[0] = *(const f16x8*)(sb_);                                    \
    srb[1] = *(const f16x8*)(sb_ + b64);                              \
    srb[2] = *(const f16x8*)(sb_ + 2 * b64);                          \
    srb[3] = *(const f16x8*)(sb_ + 3 * b64);                          \
  }
#define DSW(t)                                                        \
  {                                                                   \
    char* da_ = AsWr + (((t) & 1) ? 32768 : 0);                       \
    char* db_ = BsWr + (((t) & 1) ? 32768 : 0);                       \
    *(f16x8*)(da_) = sra[0];                                          \
    *(f16x8*)(da_ + 8192) = sra[1];                                   \
    *(f16x8*)(da_ + 16384) = sra[2];                                  \
    *(f16x8*)(da_ + 24576) = sra[3];                                  \
    *(f16x8*)(db_) = srb[0];                                          \
    *(f16x8*)(db_ + 8192) = srb[1];                                   \
    *(f16x8*)(db_ + 16384) = srb[2];                                  \
    *(f16x8*)(db_ + 24576) = srb[3];                                  \
  }

  const int ml = lane & 15, q = lane >> 4, lx = lane & 7;
  const int co0 = (q ^ lx) * 16, co1 = co0 ^ 64;
  const char* Ar = (const char*)As + wm * 16384 + ml * 128;
  const char* Br = (const char*)Bs + (wn >> 1) * 16384 + (wn & 1) * 8192 + ml * 128;

  const int nt = K >> 6;
  LDG(0);
  DSW(0);
  if (nt > 1) LDG(1);
  asm volatile("s_waitcnt lgkmcnt(0)" ::: "memory");
  __builtin_amdgcn_s_barrier();
  __builtin_amdgcn_sched_barrier(0);

  for (int t = 0; t < nt; ++t) {
    if (t + 1 < nt) {
      DSW(t + 1);
      if (t + 2 < nt) LDG(t + 2);
    }
    const int pb = (t & 1) ? 32768 : 0;
    const char* Ap = Ar + pb;
    const char* Bp = Br + pb;
    f16x8 af[8], bf[4];
#pragma unroll
    for (int ks = 0; ks < 2; ++ks) {
      const int co = ks ? co1 : co0;
#pragma unroll
      for (int i = 0; i < 8; ++i) af[i] = *(const f16x8*)(Ap + i * 2048 + co);
#pragma unroll
      for (int j = 0; j < 4; ++j) bf[j] = *(const f16x8*)(Bp + j * 2048 + co);
#pragma unroll
      for (int i = 0; i < 8; ++i)
#pragma unroll
        for (int j = 0; j < 4; ++j)
          acc[i][j] = MFMA16(bf[j], af[i], acc[i][j]);
    }
    asm volatile("s_waitcnt lgkmcnt(0)" ::: "memory");
    __builtin_amdgcn_s_barrier();
    __builtin_amdgcn_sched_barrier(0);
  }
#undef LDG
#undef DSW

#pragma unroll
  for (int j = 0; j < 4; ++j) {
    const int col0 = n0 + wn * 64 + j * 16 + q * 4;
    float4 bc = {0.f, 0.f, 0.f, 0.f};
    if constexpr (BIAS) bc = *(const float4*)(bias + col0);
#pragma unroll
    for (int i = 0; i < 8; ++i) {
      const int row = m0 + wm * 128 + i * 16 + ml;
      const float br = BROW ? bias[row] : 0.f;
      const float v0 = acc[i][j][0] + bc.x + br;
      const float v1 = acc[i][j][1] + bc.y + br;
      const float v2 = acc[i][j][2] + bc.z + br;
      const float v3 = acc[i][j][3] + bc.w + br;
      if constexpr (sizeof(CT) == 4) {
        *(float4*)(C + (size_t)row * ldc + col0) = make_float4(v0, v1, v2, v3);
      } else {
        h4 o{__float2half(v0), __float2half(v1), __float2half(v2), __float2half(v3)};
        *(h4*)((__half*)C + (size_t)row * ldc + col0) = o;
      }
    }
  }
}

// ---------------------------------------------------------------------------
// gemm_nt — R8 structure: 128x128, single 32KB LDS buffer, 3 blocks/CU (TLP),
// reg-staged LDG under MFMAs, 2 lgkm-fenced barriers/K-tile, XCD swizzle.
// ---------------------------------------------------------------------------
template <typename CT, bool BIAS, bool BROW>
__global__ __launch_bounds__(256, 3) void gemm_nt(
    const __half* __restrict__ A, int lda, long long sA,
    const __half* __restrict__ Bt, int ldb, long long sB,
    const float* __restrict__ bias, long long sBias,
    CT* __restrict__ C, int ldc, long long sC,
    int nT, int K) {
  __shared__ __align__(16) __half As[8192];
  __shared__ __align__(16) __half Bs[8192];

  const int tid = threadIdx.x;
  const int wave = tid >> 6, lane = tid & 63;

  const int cpx = gridDim.x >> 3;
  const int bid = (blockIdx.x & 7) * cpx + (blockIdx.x >> 3);

  const int gsz = 8 * nT;
  const int g = bid / gsz, r = bid % gsz;
  const int m0 = (g * 8 + (r & 7)) * 128;
  const int n0 = (r >> 3) * 128;

  A += (long long)blockIdx.z * sA;
  Bt += (long long)blockIdx.z * sB;
  C += (long long)blockIdx.z * sC;
  if constexpr (BIAS || BROW) bias += (long long)blockIdx.z * sBias;
  const int wm = wave & 1, wn = wave >> 1;

  f32x4 acc[4][4];
#pragma unroll
  for (int i = 0; i < 4; ++i)
#pragma unroll
    for (int jj = 0; jj < 4; ++jj) acc[i][jj] = (f32x4){0.f, 0.f, 0.f, 0.f};

  const int srow = tid >> 3;
  const int gc = (tid & 7) ^ (srow & 7);
  const __half* Ag = A + (size_t)(m0 + srow) * lda + gc * 8;
  const __half* Bg = Bt + (size_t)(n0 + srow) * ldb + gc * 8;
  const size_t a32 = (size_t)32 * lda, b32 = (size_t)32 * ldb;
  char* AsWr = (char*)As + tid * 16;
  char* BsWr = (char*)Bs + tid * 16;

  f16x8 sra[4], srb[4];

#define LDG(t)                                                        \
  {                                                                   \
    const __half* sa_ = Ag + (t) * 64;                                \
    const __half* sb_ = Bg + (t) * 64;                                \
    sra[0] = *(const f16x8*)(sa_);                                    \
    sra[1] = *(const f16x8*)(sa_ + a32);                              \
    sra[2] = *(const f16x8*)(sa_ + 2 * a32);                          \
    sra[3] = *(const f16x8*)(sa_ + 3 * a32);                          \
    srb[0] = *(const f16x8*)(sb_);                                    \
    srb[1] = *(const f16x8*)(sb_ + b32);                              \
    srb[2] = *(const f16x8*)(sb_ + 2 * b32);                          \
    srb[3] = *(const f16x8*)(sb_ + 3 * b32);                          \
  }
#define DSW()                                                         \
  {                                                                   \
    *(f16x8*)(AsWr) = sra[0];                                         \
    *(f16x8*)(AsWr + 4096) = sra[1];                                  \
    *(f16x8*)(AsWr + 8192) = sra[2];                                  \
    *(f16x8*)(AsWr + 12288) = sra[3];                                 \
    *(f16x8*)(BsWr) = srb[0];                                         \
    *(f16x8*)(BsWr + 4096) = srb[1];                                  \
    *(f16x8*)(BsWr + 8192) = srb[2];                                  \
    *(f16x8*)(BsWr + 12288) = srb[3];                                 \
  }

  const int ml = lane & 15, q = lane >> 4, lx = lane & 7;
  const int aoff = ((wm * 64 + ml) * 8 + (q ^ lx)) * 16;
  const int boff = ((wn * 64 + ml) * 8 + (q ^ lx)) * 16;

  const int nt = K >> 6;
  LDG(0);
  for (int t = 0; t < nt; ++t) {
    DSW();
    asm volatile("s_waitcnt lgkmcnt(0)" ::: "memory");
    __builtin_amdgcn_s_barrier();
    __builtin_amdgcn_sched_barrier(0);
    if (t + 1 < nt) LDG(t + 1);
#pragma unroll
    for (int jj = 0; jj < 2; ++jj) {
      const char* Ab = (const char*)As + (jj ? (aoff ^ 64) : aoff);
      const char* Bb = (const char*)Bs + (jj ? (boff ^ 64) : boff);
      f16x8 af[4], bf[4];
#pragma unroll
      for (int i = 0; i < 4; ++i) {
        af[i] = *(const f16x8*)(Ab + i * 2048);
        bf[i] = *(const f16x8*)(Bb + i * 2048);
      }
#pragma unroll
      for (int i = 0; i < 4; ++i)
#pragma unroll
        for (int jn = 0; jn < 4; ++jn)
          acc[i][jn] = MFMA16(bf[jn], af[i], acc[i][jn]);
    }
    asm volatile("s_waitcnt lgkmcnt(0)" ::: "memory");
    __builtin_amdgcn_s_barrier();
    __builtin_amdgcn_sched_barrier(0);
  }
#undef LDG
#undef DSW

#pragma unroll
  for (int jn = 0; jn < 4; ++jn) {
    const int col0 = n0 + wn * 64 + jn * 16 + q * 4;
    float4 bc = {0.f, 0.f, 0.f, 0.f};
    if constexpr (BIAS) bc = *(const float4*)(bias + col0);
#pragma unroll
    for (int i = 0; i < 4; ++i) {
      const int row = m0 + wm * 64 + i * 16 + ml;
      const float br = BROW ? bias[row] : 0.f;
      const float v0 = acc[i][jn][0] + bc.x + br;
      const float v1 = acc[i][jn][1] + bc.y + br;
      const float v2 = acc[i][jn][2] + bc.z + br;
      const float v3 = acc[i][jn][3] + bc.w + br;
      if constexpr (sizeof(CT) == 4) {
        *(float4*)(C + (size_t)row * ldc + col0) = make_float4(v0, v1, v2, v3);
      } else {
        h4 o{__float2half(v0), __float2half(v1), __float2half(v2), __float2half(v3)};
        *(h4*)((__half*)C + (size_t)row * ldc + col0) = o;
      }
    }
  }
}

// ---------------------------------------------------------------------------
// gemm_nt_res<GELU> — R9: Wo/W2 GEMM with FUSED residual+LN-stats epilogue.
// Same main loop as gemm_nt (K=3072 single pass, no split-K). Epilogue:
//   y[row][col] += [gelu](acc + bias[col])   (read-modify-write fp32 y)
// and per-block (S,SS) partial -> part[batch*48 + mtile*6 + ntile].
// Replaces the split-K partials (38.6MB w + 38.6MB r) + residual_stats pass
// (2 launches, ~90MB each). M=8192, N=768 -> grid 384 (%8==0 for swizzle);
// 128-row tiles never cross a batch boundary (1024 % 128 == 0).
// ---------------------------------------------------------------------------
template <bool GELU>
__global__ __launch_bounds__(256, 3) void gemm_nt_res(
    const __half* __restrict__ A, int lda,
    const __half* __restrict__ Bt, int ldb,
    const float* __restrict__ bias, float* __restrict__ y,
    float2* __restrict__ part, int nT, int K) {
  __shared__ __align__(16) __half As[8192];
  __shared__ __align__(16) __half Bs[8192];

  const int tid = threadIdx.x;
  const int wave = tid >> 6, lane = tid & 63;

  const int cpx = gridDim.x >> 3;
  const int bid = (blockIdx.x & 7) * cpx + (blockIdx.x >> 3);

  const int gsz = 8 * nT;
  const int g = bid / gsz, r = bid % gsz;
  const int m0 = (g * 8 + (r & 7)) * 128;
  const int n0 = (r >> 3) * 128;
  const int wm = wave & 1, wn = wave >> 1;

  f32x4 acc[4][4];
#pragma unroll
  for (int i = 0; i < 4; ++i)
#pragma unroll
    for (int jj = 0; jj < 4; ++jj) acc[i][jj] = (f32x4){0.f, 0.f, 0.f, 0.f};

  const int srow = tid >> 3;
  const int gc = (tid & 7) ^ (srow & 7);
  const __half* Ag = A + (size_t)(m0 + srow) * lda + gc * 8;
  const __half* Bg = Bt + (size_t)(n0 + srow) * ldb + gc * 8;
  const size_t a32 = (size_t)32 * lda, b32 = (size_t)32 * ldb;
  char* AsWr = (char*)As + tid * 16;
  char* BsWr = (char*)Bs + tid * 16;

  f16x8 sra[4], srb[4];

#define LDG(t)                                                        \
  {                                                                   \
    const __half* sa_ = Ag + (t) * 64;                                \
    const __half* sb_ = Bg + (t) * 64;                                \
    sra[0] = *(const f16x8*)(sa_);                                    \
    sra[1] = *(const f16x8*)(sa_ + a32);                              \
    sra[2] = *(const f16x8*)(sa_ + 2 * a32);                          \
    sra[3] = *(const f16x8*)(sa_ + 3 * a32);                          \
    srb[0] = *(const f16x8*)(sb_);                                    \
    srb[1] = *(const f16x8*)(sb_ + b32);                              \
    srb[2] = *(const f16x8*)(sb_ + 2 * b32);                          \
    srb[3] = *(const f16x8*)(sb_ + 3 * b32);                          \
  }
#define DSW()                                                         \
  {                                                                   \
    *(f16x8*)(AsWr) = sra[0];                                         \
    *(f16x8*)(AsWr + 4096) = sra[1];                                  \
    *(f16x8*)(AsWr + 8192) = sra[2];                                  \
    *(f16x8*)(AsWr + 12288) = sra[3];                                 \
    *(f16x8*)(BsWr) = srb[0];                                         \
    *(f16x8*)(BsWr + 4096) = srb[1];                                  \
    *(f16x8*)(BsWr + 8192) = srb[2];                                  \
    *(f16x8*)(BsWr + 12288) = srb[3];                                 \
  }

  const int ml = lane & 15, q = lane >> 4, lx = lane & 7;
  const int aoff = ((wm * 64 + ml) * 8 + (q ^ lx)) * 16;
  const int boff = ((wn * 64 + ml) * 8 + (q ^ lx)) * 16;

  const int nt = K >> 6;
  LDG(0);
  for (int t = 0; t < nt; ++t) {
    DSW();
    asm volatile("s_waitcnt lgkmcnt(0)" ::: "memory");
    __builtin_amdgcn_s_barrier();
    __builtin_amdgcn_sched_barrier(0);
    if (t + 1 < nt) LDG(t + 1);
#pragma unroll
    for (int jj = 0; jj < 2; ++jj) {
      const char* Ab = (const char*)As + (jj ? (aoff ^ 64) : aoff);
      const char* Bb = (const char*)Bs + (jj ? (boff ^ 64) : boff);
      f16x8 af[4], bf[4];
#pragma unroll
      for (int i = 0; i < 4; ++i) {
        af[i] = *(const f16x8*)(Ab + i * 2048);
        bf[i] = *(const f16x8*)(Bb + i * 2048);
      }
#pragma unroll
      for (int i = 0; i < 4; ++i)
#pragma unroll
        for (int jn = 0; jn < 4; ++jn)
          acc[i][jn] = MFMA16(bf[jn], af[i], acc[i][jn]);
    }
    asm volatile("s_waitcnt lgkmcnt(0)" ::: "memory");
    __builtin_amdgcn_s_barrier();
    __builtin_amdgcn_sched_barrier(0);
  }
#undef LDG
#undef DSW

  // fused epilogue: y += [gelu](acc + bias); block partial (S,SS)
  float s = 0.f, ss = 0.f;
#pragma unroll
  for (int jn = 0; jn < 4; ++jn) {
    const int col0 = n0 + wn * 64 + jn * 16 + q * 4;
    const float4 bc = *(const float4*)(bias + col0);
#pragma unroll
    for (int i = 0; i < 4; ++i) {
      const int row = m0 + wm * 64 + i * 16 + ml;
      float* yp = y + (size_t)row * 768 + col0;
      const float4 yv = *(const float4*)yp;
      float a0 = acc[i][jn][0] + bc.x, a1 = acc[i][jn][1] + bc.y;
      float a2 = acc[i][jn][2] + bc.z, a3 = acc[i][jn][3] + bc.w;
      if constexpr (GELU) {
        a0 = gelu_exact(a0); a1 = gelu_exact(a1);
        a2 = gelu_exact(a2); a3 = gelu_exact(a3);
      }
      const float v0 = yv.x + a0, v1 = yv.y + a1, v2 = yv.z + a2, v3 = yv.w + a3;
      *(float4*)yp = make_float4(v0, v1, v2, v3);
      s += v0 + v1 + v2 + v3;
      ss += v0 * v0 + v1 * v1 + v2 * v2 + v3 * v3;
    }
  }
  s = waveReduceSum(s);
  ss = waveReduceSum(ss);
  __shared__ float2 wr[4];
  if (lane == 0) wr[wave] = make_float2(s, ss);
  __syncthreads();
  if (tid == 0) {
    const float S = wr[0].x + wr[1].x + wr[2].x + wr[3].x;
    const float SS = wr[0].y + wr[1].y + wr[2].y + wr[3].y;
    // 48 tiles per batch: 8 M-tiles x 6 N-tiles
    const int idx = (m0 >> 10) * 48 + ((m0 >> 7) & 7) * 6 + (n0 >> 7);
    part[idx] = make_float2(S, SS);
  }
}

// ---------------------------------------------------------------------------
// prep: all 6 weight transposes (fp32 -> fp16) + bias concat. grid (2305, 6).
// ---------------------------------------------------------------------------
__global__ __launch_bounds__(256) void prep(
    const float* __restrict__ Wq, const float* __restrict__ Wk,
    const float* __restrict__ Wv, const float* __restrict__ W1,
    const float* __restrict__ Wo, const float* __restrict__ W2,
    const float* __restrict__ bq, const float* __restrict__ bk,
    __half* __restrict__ wD, __half* __restrict__ wB, __half* __restrict__ wC,
    __half* __restrict__ wA, float* __restrict__ bqk) {
  if (blockIdx.x == 2304) {
    if (blockIdx.y == 0)
      for (int i = threadIdx.x; i < 3072; i += 256) {
        bqk[i] = bq[i];
        bqk[3072 + i] = bk[i];
      }
    return;
  }
  __shared__ float t[32][33];
  const int tx = threadIdx.x & 31, ty = threadIdx.x >> 5;
  if (blockIdx.y < 4) {
    const float* in;
    __half* out;
    switch (blockIdx.y) {
      case 0: in = Wq; out = wD; break;
      case 1: in = Wk; out = wD + 3072 * 768; break;
      case 2: in = Wv; out = wB; break;
      default: in = W1; out = wC; break;
    }
    const int cb = blockIdx.x % 96, rb = blockIdx.x / 96;
    const int c = cb * 32 + tx, r0 = rb * 32;
#pragma unroll
    for (int i = 0; i < 32; i += 8) t[ty + i][tx] = in[(size_t)(r0 + ty + i) * 3072 + c];
    __syncthreads();
    const int oc = r0 + tx, o0 = cb * 32;
#pragma unroll
    for (int i = 0; i < 32; i += 8)
      out[(size_t)(o0 + ty + i) * 768 + oc] = __float2half(t[tx][ty + i]);
  } else {
    const float* in = (blockIdx.y == 5) ? W2 : Wo;
    __half* out = wA + ((blockIdx.y == 5) ? 3072 * 768 : 0);
    const int cb = blockIdx.x % 24, rb = blockIdx.x / 24;
    const int c = cb * 32 + tx, r0 = rb * 32;
#pragma unroll
    for (int i = 0; i < 32; i += 8) t[ty + i][tx] = in[(size_t)(r0 + ty + i) * 768 + c];
    __syncthreads();
    const int oc = r0 + tx, o0 = cb * 32;
#pragma unroll
    for (int i = 0; i < 32; i += 8)
      out[(size_t)(o0 + ty + i) * 3072 + oc] = __float2half(t[tx][ty + i]);
  }
}

// ---------------------------------------------------------------------------
__global__ __launch_bounds__(256) void embed_pos_kernel(
    const int* __restrict__ x, const float* __restrict__ emb,
    float* __restrict__ y, __half* __restrict__ yh) {
  const int row = blockIdx.x;  // b*1024 + s
  const int s = row & 1023;
  const int tok = x[row];
  const float* ep = emb + (size_t)tok * 768;
  float* yp = y + (size_t)row * 768;
  __half* hp = yh + (size_t)row * 768;
  const float c = -13.287712379549449f / 768.f;  // -log2(10000)/768
  for (int d = threadIdx.x; d < 768; d += 256) {
    float ang = (float)s * exp2f((float)d * c);
    float pe = (d & 1) ? cosf(ang) : sinf(ang);
    float v = ep[d] + pe;
    yp[d] = v;
    hp[d] = __float2half(v);
  }
}

// Row softmax over 1024 fp32 logits -> fp16 probs. One block per row.
__global__ __launch_bounds__(256) void softmax_rows(
    const float* __restrict__ L, __half* __restrict__ P) {
  const size_t row = blockIdx.x;
  const float4 x = ((const float4*)(L + row * 1024))[threadIdx.x];
  const int wave = threadIdx.x >> 6, lane = threadIdx.x & 63;
  float m = fmaxf(fmaxf(x.x, x.y), fmaxf(x.z, x.w));
  m = waveReduceMax(m);
  __shared__ float sm[4];
  __shared__ float ssum[4];
  if (lane == 0) sm[wave] = m;
  __syncthreads();
  m = fmaxf(fmaxf(sm[0], sm[1]), fmaxf(sm[2], sm[3]));
  float e0 = expf(x.x - m), e1 = expf(x.y - m), e2 = expf(x.z - m), e3 = expf(x.w - m);
  float s = e0 + e1 + e2 + e3;
  s = waveReduceSum(s);
  if (lane == 0) ssum[wave] = s;
  __syncthreads();
  s = ssum[0] + ssum[1] + ssum[2] + ssum[3];
  const float inv = 1.f / s;
  h4 o{__float2half(e0 * inv), __float2half(e1 * inv), __float2half(e2 * inv),
       __float2half(e3 * inv)};
  ((h4*)(P + row * 1024))[threadIdx.x] = o;
}

// Finalize (reduce 48 partials in-block) + apply LN; grid 6144.
template <bool WB>
__global__ __launch_bounds__(256) void ln_apply(
    float* __restrict__ y, __half* __restrict__ yh, const float* __restrict__ w,
    const float* __restrict__ bb, const float2* __restrict__ partials) {
  const unsigned i4 = blockIdx.x * 256 + threadIdx.x;
  const unsigned i = i4 * 4;
  const unsigned b = i / 786432u;
  const int tid = threadIdx.x;
  float s = 0.f, ss = 0.f;
  if (tid < 48) {
    float2 p = partials[b * 48 + tid];
    s = p.x;
    ss = p.y;
  }
  s = waveReduceSum(s);
  ss = waveReduceSum(ss);
  __shared__ float2 wsum[4];
  if ((tid & 63) == 0) wsum[tid >> 6] = make_float2(s, ss);
  __syncthreads();
  const float S = wsum[0].x + wsum[1].x + wsum[2].x + wsum[3].x;
  const float SS = wsum[0].y + wsum[1].y + wsum[2].y + wsum[3].y;
  const float inv = 1.f / 786432.f;
  const float mean = S * inv;
  const float rstd = rsqrtf(SS * inv - mean * mean + 1e-5f);

  const unsigned e4 = (i - b * 786432u) >> 2;
  float4 yv = ((const float4*)y)[i4];
  const float4 wv = ((const float4*)w)[e4];
  const float4 bv = ((const float4*)bb)[e4];
  float4 r;
  r.x = (yv.x - mean) * rstd * wv.x + bv.x;
  r.y = (yv.y - mean) * rstd * wv.y + bv.y;
  r.z = (yv.z - mean) * rstd * wv.z + bv.z;
  r.w = (yv.w - mean) * rstd * wv.w + bv.w;
  ((float4*)y)[i4] = r;
  if constexpr (WB) {
    h4 o{__float2half(r.x), __float2half(r.y), __float2half(r.z), __float2half(r.w)};
    ((h4*)yh)[i4] = o;
  }
}

// ---------------------------------------------------------------------------
extern "C" void kernel_launch(void* const* d_in, const int* in_sizes, int n_in,
                              void* d_out, int out_size, void* d_ws, size_t ws_size,
                              hipStream_t stream) {
  const int* x = (const int*)d_in[0];
  const float* emb = (const float*)d_in[1];
  const float* Wq = (const float*)d_in[2];
  const float* bq = (const float*)d_in[3];
  const float* Wk = (const float*)d_in[4];
  const float* bk = (const float*)d_in[5];
  const float* Wv = (const float*)d_in[6];
  const float* bv = (const float*)d_in[7];
  const float* Wo = (const float*)d_in[8];
  const float* bo = (const float*)d_in[9];
  const float* W1 = (const float*)d_in[10];
  const float* b1 = (const float*)d_in[11];
  const float* W2 = (const float*)d_in[12];
  const float* b2 = (const float*)d_in[13];
  const float* ln1w = (const float*)d_in[14];
  const float* ln1b = (const float*)d_in[15];
  const float* ln2w = (const float*)d_in[16];
  const float* ln2b = (const float*)d_in[17];

  float* y = (float*)d_out;  // [8,1024,768] fp32 residual stream

  // ---- workspace map (liveness overlays), total 225.5 MB ----
  char* ws = (char*)d_ws;
  __half* yh = (__half*)(ws + 0);            // 12.58 MB fp16 residual stream
  __half* qb = (__half*)(ws + 12582912);     // 50.33 MB q -> av -> f1
  __half* kb = (__half*)(ws + 62914560);     // 50.33 MB k -> Ph
  __half* Ph = kb;
  __half* vT = (__half*)(ws + 113246208);    // 50.33 MB v^T (dead after av)
  float* Lg = (float*)(ws + 163577856);      // 33.55 MB logits fp32
  __half* wA = (__half*)(ws + 197132288);    // 9.44 MB Wo^T|W2^T
  __half* wD = (__half*)(ws + 206569472);    // 9.44 MB Wq^T|Wk^T
  __half* wB = (__half*)(ws + 216006656);    // 4.72 MB Wv^T
  __half* wC = (__half*)(ws + 220725248);    // 4.72 MB W1^T
  float* bqk = (float*)(ws + 225443840);     // 24 KB bq|bk
  float2* part = (float2*)(ws + 225468416);  // 3 KB (8*48 float2)
  const size_t WS_NEEDED = 225474624;
  if (ws_size < WS_NEEDED) return;

  const dim3 blk(256), blk8(512);
  const long long SH = 1024LL * 3072, SS = 1024LL * 1024;
  const long long HALF = 25165824;  // q->k element stride (8192*3072)

  prep<<<dim3(2305, 6), blk, 0, stream>>>(Wq, Wk, Wv, W1, Wo, W2, bq, bk, wD, wB, wC, wA, bqk);
  embed_pos_kernel<<<dim3(8192), blk, 0, stream>>>(x, emb, y, yh);

  // q,k = yh @ {Wq,Wk} + {bq,bk}: M=8192 N=3072 K=768
  gemm_nt8<__half, true, false><<<dim3(384, 1, 2), blk8, 0, stream>>>(
      yh, 768, 0, wD, 768, 3072LL * 768, bqk, 3072, qb, 3072, HALF, 12, 768);

  // vT[b][n][s] = sum_k Wv[k][n]*y[b][s][k] + bv[n]
  gemm_nt<__half, false, true><<<dim3(192, 1, 8), blk, 0, stream>>>(
      wB, 768, 0, yh, 768, 1024LL * 768, bv, 0, vT, 1024, SH, 8, 768);

  // logits = q k^T (fp32), per batch
  gemm_nt<float, false, false><<<dim3(64, 1, 8), blk, 0, stream>>>(
      qb, 3072, SH, kb, 3072, SH, nullptr, 0, Lg, 1024, SS, 8, 3072);

  softmax_rows<<<dim3(8192), blk, 0, stream>>>(Lg, Ph);  // Ph overlays k (dead)

  // av = P @ V (Bt = v^T), per batch; av overlays q
  gemm_nt<__half, false, false><<<dim3(192, 1, 8), blk, 0, stream>>>(
      Ph, 1024, SS, vT, 1024, SH, nullptr, 0, (__half*)qb, 3072, SH, 24, 1024);

  // y += av @ Wo + bo, fused LN1 stats (K=3072 single pass, 384 blocks)
  gemm_nt_res<false><<<dim3(384), blk, 0, stream>>>(
      (__half*)qb, 3072, wA, 3072, bo, y, part, 6, 3072);
  ln_apply<true><<<dim3(6144), blk, 0, stream>>>(y, yh, ln1w, ln1b, part);

  // f1 = y@W1 + b1 (fp16 -> qb, overlays av)
  gemm_nt<__half, true, false><<<dim3(1536, 1, 1), blk, 0, stream>>>(
      yh, 768, 0, wC, 768, 0, b1, 0, (__half*)qb, 3072, 0, 24, 768);

  // y += gelu(f1 @ W2 + b2), fused LN2 stats
  gemm_nt_res<true><<<dim3(384), blk, 0, stream>>>(
      (__half*)qb, 3072, wA + 3072 * 768, 3072, b2, y, part, 6, 3072);
  ln_apply<false><<<dim3(6144), blk, 0, stream>>>(y, nullptr, ln2w, ln2b, part);
}